// Round 17
// baseline (207.735 us; speedup 1.0000x reference)
//
#include <hip/hip_runtime.h>

typedef __attribute__((ext_vector_type(8))) short bf16x8;
typedef __attribute__((ext_vector_type(4))) float f32x4;

#define MFMA16(A,B,C) __builtin_amdgcn_mfma_f32_16x16x32_bf16(A,B,C,0,0,0)

__device__ __forceinline__ unsigned short f2bf(float f){
  unsigned int u = __float_as_uint(f);
  u += 0x7FFFu + ((u >> 16) & 1u);        // round-to-nearest-even
  return (unsigned short)(u >> 16);
}
__device__ __forceinline__ float bf2f(unsigned short s){
  return __uint_as_float(((unsigned int)s) << 16);
}
// byte offset into a [rows][64] bf16 LDS tile (128B rows), XOR-swizzled (G4)
__device__ __forceinline__ int swz(int row, int kbyte){
  return (row * 128 + kbyte) ^ ((row & 7) << 4);
}

// -- prep (merged): weight transposes + x->bf16 + bias gather, range-split --
__global__ __launch_bounds__(256) void k_prep(
    const float* __restrict__ w_qkv, const float* __restrict__ w_out,
    const float* __restrict__ x,
    const int* __restrict__ hop, const float* __restrict__ rpe_bias,
    unsigned short* __restrict__ wqT, unsigned short* __restrict__ woT,
    unsigned short* __restrict__ xb, unsigned short* __restrict__ biasT)
{
  __shared__ float rl[72];
  const int tid = threadIdx.x;
  if (tid < 72) rl[tid] = rpe_bias[tid];
  __syncthreads();
  int idx = blockIdx.x * 256 + tid;
  if (idx < 786432) {                          // wqT: (512,1536) -> n-major
    int n = idx >> 9, kq = idx & 511;
    wqT[idx] = f2bf(w_qkv[(size_t)kq * 1536 + n]);
  } else if (idx < 1048576) {                  // woT: (512,512) -> n-major
    int j = idx - 786432;
    int n = j >> 9, kq = j & 511;
    woT[j] = f2bf(w_out[(size_t)kq * 512 + n]);
  } else if (idx < 2097152) {                  // xb: 4 f32 -> 4 bf16 each
    int j = idx - 1048576;
    float4 xv = *reinterpret_cast<const float4*>(x + (size_t)j * 4);
    ushort4 o;
    o.x = f2bf(xv.x); o.y = f2bf(xv.y); o.z = f2bf(xv.z); o.w = f2bf(xv.w);
    *reinterpret_cast<ushort4*>(xb + (size_t)j * 4) = o;
  } else {                                     // biasT[h][v][w], w contiguous
    int j = idx - 2097152;                     // (v,w) flat, coalesced
    int hv = hop[j];
#pragma unroll
    for (int h = 0; h < 8; ++h)
      biasT[((size_t)h << 20) + j] = f2bf(rl[h * 9 + hv]);
  }
}

// ---------------- QKV GEMM: qkv = xb @ w_qkv (MFMA, bf16 in / f32 acc) -----
__global__ __launch_bounds__(256) void k_qkv(
    const unsigned short* __restrict__ xb, const unsigned short* __restrict__ wqT,
    unsigned short* __restrict__ q, unsigned short* __restrict__ k_,
    unsigned short* __restrict__ valT)
{
  __shared__ char lds[32768];
  char* At = lds; char* Bt = lds + 16384;
  const int tid = threadIdx.x;
  const int wid = tid >> 6, lane = tid & 63, g = lane >> 4, r = lane & 15;
  const int wm = wid >> 1, wn = wid & 1;
  const int m0 = blockIdx.x * 128, n0 = blockIdx.y * 128;

  f32x4 acc[4][4];
#pragma unroll
  for (int a = 0; a < 4; ++a)
#pragma unroll
    for (int b = 0; b < 4; ++b) acc[a][b] = (f32x4){0.f, 0.f, 0.f, 0.f};

  for (int kt = 0; kt < 8; ++kt) {
    const int k0 = kt * 64;
    __syncthreads();
#pragma unroll
    for (int it = 0; it < 4; ++it) {
      int c = tid + it * 256;            // 128 rows x 8 chunks(16B)
      int row = c >> 3, c8 = c & 7;
      *reinterpret_cast<uint4*>(At + swz(row, c8 * 16)) =
          *reinterpret_cast<const uint4*>(xb + (size_t)(m0 + row) * 512 + k0 + c8 * 8);
      *reinterpret_cast<uint4*>(Bt + swz(row, c8 * 16)) =
          *reinterpret_cast<const uint4*>(wqT + (size_t)(n0 + row) * 512 + k0 + c8 * 8);
    }
    __syncthreads();
#pragma unroll
    for (int kk = 0; kk < 2; ++kk) {
      bf16x8 af[4], bf[4];
      const int kb = (kk * 32 + 8 * g) * 2;
#pragma unroll
      for (int mi = 0; mi < 4; ++mi)
        af[mi] = *reinterpret_cast<const bf16x8*>(At + swz(wm * 64 + mi * 16 + r, kb));
#pragma unroll
      for (int ni = 0; ni < 4; ++ni)
        bf[ni] = *reinterpret_cast<const bf16x8*>(Bt + swz(wn * 64 + ni * 16 + r, kb));
#pragma unroll
      for (int mi = 0; mi < 4; ++mi)
#pragma unroll
        for (int ni = 0; ni < 4; ++ni)
          acc[mi][ni] = MFMA16(af[mi], bf[ni], acc[mi][ni]);
    }
  }
  const int s = n0 >> 9;  // 0=q 1=k 2=val
#pragma unroll
  for (int mi = 0; mi < 4; ++mi)
#pragma unroll
    for (int ni = 0; ni < 4; ++ni)
#pragma unroll
      for (int i = 0; i < 4; ++i) {
        int m = m0 + wm * 64 + mi * 16 + 4 * g + i;   // D row = 4g+i (m89)
        int n = n0 + wn * 64 + ni * 16 + r;           // D col = lane&15
        int b = m >> 10, v = m & 1023;
        int cc = n & 511, h = cc >> 6, d = cc & 63;
        int bh = b * 8 + h;
        unsigned short bfv = f2bf(acc[mi][ni][i]);
        if (s == 2)      valT[((size_t)bh * 64 + d) * 1024 + v] = bfv;
        else if (s == 0) q [((size_t)bh * 1024 + v) * 64 + d] = bfv;
        else             k_[((size_t)bh * 1024 + v) * 64 + d] = bfv;
      }
}

// ---------------- attention: named-reg scores + shfl softmax + PV ----------
// One block = (b,h, 16 q-rows). Wave w owns score cols [256w, 256w+256).
// This round's A/B: (1) attn write is PLAIN stores (nt removed — let L2
// buffer the 268MB stream); (2) first 4 ct's K fragments prefetched BEFORE
// the staging barrier (hides L2 latency under bias staging).
#define PSTR 1032
__global__ __launch_bounds__(256, 3) void k_attn(
    const unsigned short* __restrict__ q, const unsigned short* __restrict__ k_,
    const unsigned short* __restrict__ valT,
    const unsigned short* __restrict__ biasT,
    float* __restrict__ attn, unsigned short* __restrict__ oh)
{
  __shared__ unsigned short P[16 * PSTR];   // bf16, 33 KB
  __shared__ float red[2][4][16];
  const int tid = threadIdx.x;
  const int wid = tid >> 6, lane = tid & 63, g = lane >> 4, r = lane & 15;
  // bijective XCD swizzle (4096 % 8 == 0): XCD j gets work ids [512j, 512j+512)
  const int blk = ((blockIdx.x & 7) << 9) | (blockIdx.x >> 3);
  const int h  = blk >> 9;                  // outermost: one head per XCD
  const int vt = (blk >> 3) & 63;
  const int b  = blk & 7;                   // innermost: bias-tile sharers adjacent
  const int bh = b * 8 + h;
  const int v0 = vt * 16;

  // stage bias tile [16 rows][1024 w] bf16 into P (uint4 = 8 elems, coalesced)
  const unsigned short* bb = biasT + ((size_t)h << 20) + (size_t)v0 * 1024;
#pragma unroll
  for (int it = 0; it < 8; ++it) {
    int e = tid + it * 256;                  // 0..2047: row=e>>7, chunk=e&127
    int row = e >> 7, c8 = e & 127;
    *reinterpret_cast<uint4*>(&P[row * PSTR + c8 * 8]) =
        *reinterpret_cast<const uint4*>(bb + (size_t)row * 1024 + c8 * 8);
  }

  // Q fragments + first-4-ct K fragments in registers, issued BEFORE barrier
  const unsigned short* qp = q + ((size_t)bh * 1024 + v0) * 64;
  bf16x8 qf0 = *reinterpret_cast<const bf16x8*>(qp + r * 64 + 8 * g);
  bf16x8 qf1 = *reinterpret_cast<const bf16x8*>(qp + r * 64 + 32 + 8 * g);
  const unsigned short* kb = k_ + (size_t)bh * 65536;
  const int w0 = wid * 256 + r;
  bf16x8 pka0 = *reinterpret_cast<const bf16x8*>(kb + (size_t)(w0     ) * 64 + 8 * g);
  bf16x8 pkb0 = *reinterpret_cast<const bf16x8*>(kb + (size_t)(w0     ) * 64 + 32 + 8 * g);
  bf16x8 pka1 = *reinterpret_cast<const bf16x8*>(kb + (size_t)(w0 + 16) * 64 + 8 * g);
  bf16x8 pkb1 = *reinterpret_cast<const bf16x8*>(kb + (size_t)(w0 + 16) * 64 + 32 + 8 * g);
  bf16x8 pka2 = *reinterpret_cast<const bf16x8*>(kb + (size_t)(w0 + 32) * 64 + 8 * g);
  bf16x8 pkb2 = *reinterpret_cast<const bf16x8*>(kb + (size_t)(w0 + 32) * 64 + 32 + 8 * g);
  bf16x8 pka3 = *reinterpret_cast<const bf16x8*>(kb + (size_t)(w0 + 48) * 64 + 8 * g);
  bf16x8 pkb3 = *reinterpret_cast<const bf16x8*>(kb + (size_t)(w0 + 48) * 64 + 32 + 8 * g);
  __syncthreads();

  // QK: scores in named registers; bias from LDS
  f32x4 s0, s1, s2, s3, s4, s5, s6, s7, s8, s9, s10, s11, s12, s13, s14, s15;

#define QK_BIAS(ct) {                                                          \
    const int wcol = wid * 256 + ct * 16 + r;                                  \
    s##ct[0] = (acc[0] + bf2f(P[(4 * g + 0) * PSTR + wcol])) * 0.125f;         \
    s##ct[1] = (acc[1] + bf2f(P[(4 * g + 1) * PSTR + wcol])) * 0.125f;         \
    s##ct[2] = (acc[2] + bf2f(P[(4 * g + 2) * PSTR + wcol])) * 0.125f;         \
    s##ct[3] = (acc[3] + bf2f(P[(4 * g + 3) * PSTR + wcol])) * 0.125f; }
#define QK_PRE(ct) {                                                           \
    f32x4 acc = (f32x4){0.f, 0.f, 0.f, 0.f};                                   \
    acc = MFMA16(qf0, pka##ct, acc);                                           \
    acc = MFMA16(qf1, pkb##ct, acc);                                           \
    QK_BIAS(ct) }
#define QK_CT(ct) {                                                            \
    const int wc = wid * 256 + ct * 16 + r;                                    \
    f32x4 acc = (f32x4){0.f, 0.f, 0.f, 0.f};                                   \
    bf16x8 kfa = *reinterpret_cast<const bf16x8*>(kb + (size_t)wc * 64 + 8 * g);        \
    bf16x8 kfb = *reinterpret_cast<const bf16x8*>(kb + (size_t)wc * 64 + 32 + 8 * g);   \
    acc = MFMA16(qf0, kfa, acc);                                               \
    acc = MFMA16(qf1, kfb, acc);                                               \
    QK_BIAS(ct) }
  QK_PRE(0)  QK_PRE(1)  QK_PRE(2)  QK_PRE(3)
  QK_CT(4)  QK_CT(5)  QK_CT(6)  QK_CT(7)
  QK_CT(8)  QK_CT(9)  QK_CT(10) QK_CT(11)
  QK_CT(12) QK_CT(13) QK_CT(14) QK_CT(15)
#undef QK_CT
#undef QK_PRE
#undef QK_BIAS

  // per-row max: local over ct (componentwise), shfl over 16-lane r-group
  f32x4 m4 = s0;
#define MX_CT(ct) { m4[0] = fmaxf(m4[0], s##ct[0]); m4[1] = fmaxf(m4[1], s##ct[1]); \
                    m4[2] = fmaxf(m4[2], s##ct[2]); m4[3] = fmaxf(m4[3], s##ct[3]); }
  MX_CT(1)  MX_CT(2)  MX_CT(3)  MX_CT(4)  MX_CT(5)  MX_CT(6)  MX_CT(7)
  MX_CT(8)  MX_CT(9)  MX_CT(10) MX_CT(11) MX_CT(12) MX_CT(13) MX_CT(14) MX_CT(15)
#undef MX_CT
#pragma unroll
  for (int o = 1; o <= 8; o <<= 1)
#pragma unroll
    for (int i = 0; i < 4; ++i) m4[i] = fmaxf(m4[i], __shfl_xor(m4[i], o, 64));
  if (r == 0)
#pragma unroll
    for (int i = 0; i < 4; ++i) red[0][wid][4 * g + i] = m4[i];
  __syncthreads();
#pragma unroll
  for (int i = 0; i < 4; ++i) {
    float M = red[0][0][4 * g + i];
#pragma unroll
    for (int w = 1; w < 4; ++w) M = fmaxf(M, red[0][w][4 * g + i]);
    m4[i] = M;
  }

  // exp + per-row sum
  f32x4 sm4 = (f32x4){0.f, 0.f, 0.f, 0.f};
#define EX_CT(ct) { s##ct[0] = __expf(s##ct[0] - m4[0]); sm4[0] += s##ct[0];   \
                    s##ct[1] = __expf(s##ct[1] - m4[1]); sm4[1] += s##ct[1];   \
                    s##ct[2] = __expf(s##ct[2] - m4[2]); sm4[2] += s##ct[2];   \
                    s##ct[3] = __expf(s##ct[3] - m4[3]); sm4[3] += s##ct[3]; }
  EX_CT(0)  EX_CT(1)  EX_CT(2)  EX_CT(3)  EX_CT(4)  EX_CT(5)  EX_CT(6)  EX_CT(7)
  EX_CT(8)  EX_CT(9)  EX_CT(10) EX_CT(11) EX_CT(12) EX_CT(13) EX_CT(14) EX_CT(15)
#undef EX_CT
#pragma unroll
  for (int o = 1; o <= 8; o <<= 1)
#pragma unroll
    for (int i = 0; i < 4; ++i) sm4[i] += __shfl_xor(sm4[i], o, 64);
  if (r == 0)
#pragma unroll
    for (int i = 0; i < 4; ++i) red[1][wid][4 * g + i] = sm4[i];
  __syncthreads();                 // all QK bias reads done before P overwrite
  f32x4 inv4;
#pragma unroll
  for (int i = 0; i < 4; ++i) {
    float T = red[1][0][4 * g + i] + red[1][1][4 * g + i] +
              red[1][2][4 * g + i] + red[1][3][4 * g + i];
    inv4[i] = 1.0f / T;
  }

  // normalize into bf16 P only (no scattered global writes)
#define NW_CT(ct) {                                                            \
    const int col = wid * 256 + ct * 16 + r;                                   \
    P[(4 * g + 0) * PSTR + col] = f2bf(s##ct[0] * inv4[0]);                    \
    P[(4 * g + 1) * PSTR + col] = f2bf(s##ct[1] * inv4[1]);                    \
    P[(4 * g + 2) * PSTR + col] = f2bf(s##ct[2] * inv4[2]);                    \
    P[(4 * g + 3) * PSTR + col] = f2bf(s##ct[3] * inv4[3]); }
  NW_CT(0)  NW_CT(1)  NW_CT(2)  NW_CT(3)  NW_CT(4)  NW_CT(5)  NW_CT(6)  NW_CT(7)
  NW_CT(8)  NW_CT(9)  NW_CT(10) NW_CT(11) NW_CT(12) NW_CT(13) NW_CT(14) NW_CT(15)
#undef NW_CT
  __syncthreads();

  // PV first: out(16x64) = P(16x1024) @ val(1024x64); wave owns 16 out cols.
  const unsigned short* vT = valT + ((size_t)bh * 64 + wid * 16) * 1024;
  f32x4 a0 = (f32x4){0.f,0.f,0.f,0.f}, a1 = a0;
  for (int kc = 0; kc < 32; kc += 2) {
    const int base = r * PSTR, vbase = kc * 32 + 8 * g;
    bf16x8 p0 = *reinterpret_cast<const bf16x8*>(&P[base + vbase]);
    bf16x8 p1 = *reinterpret_cast<const bf16x8*>(&P[base + vbase + 32]);
    bf16x8 v0_ = *reinterpret_cast<const bf16x8*>(vT + (size_t)r * 1024 + vbase);
    bf16x8 v1_ = *reinterpret_cast<const bf16x8*>(vT + (size_t)r * 1024 + vbase + 32);
    a0 = MFMA16(p0, v0_, a0);
    a1 = MFMA16(p1, v1_, a1);
  }
  f32x4 acc = a0 + a1;
#pragma unroll
  for (int i = 0; i < 4; ++i) {
    size_t oi = ((size_t)(b * 1024 + v0 + 4 * g + i)) * 512 + h * 64 + wid * 16 + r;
    oh[oi] = f2bf(acc[i]);
  }

  // attn write last: PLAIN stores (L2-buffered), f32x4 16B, 1KB/wave chunks.
  float* ab = attn + ((size_t)bh * 1024 + v0) * 1024;
#pragma unroll
  for (int it = 0; it < 16; ++it) {
    int e = tid + it * 256;                 // 0..4095: row=e>>8, quad=e&255
    int row = e >> 8, q4 = e & 255;
    uint2 pv = *reinterpret_cast<const uint2*>(&P[row * PSTR + q4 * 4]);
    f32x4 o;
    o[0] = bf2f((unsigned short)(pv.x      ));
    o[1] = bf2f((unsigned short)(pv.x >> 16));
    o[2] = bf2f((unsigned short)(pv.y      ));
    o[3] = bf2f((unsigned short)(pv.y >> 16));
    *reinterpret_cast<f32x4*>(ab + (size_t)row * 1024 + q4 * 4) = o;
  }
}

// ---------------- output GEMM: out = oh @ w_out + b_out (f32 out) ----------
__global__ __launch_bounds__(256) void k_out(
    const unsigned short* __restrict__ oh, const unsigned short* __restrict__ woT,
    const float* __restrict__ b_out, float* __restrict__ out)
{
  __shared__ char lds[32768];
  char* At = lds; char* Bt = lds + 16384;
  const int tid = threadIdx.x;
  const int wid = tid >> 6, lane = tid & 63, g = lane >> 4, r = lane & 15;
  const int wm = wid >> 1, wn = wid & 1;
  const int m0 = blockIdx.x * 128, n0 = blockIdx.y * 128;

  f32x4 acc[4][4];
#pragma unroll
  for (int a = 0; a < 4; ++a)
#pragma unroll
    for (int b = 0; b < 4; ++b) acc[a][b] = (f32x4){0.f, 0.f, 0.f, 0.f};

  for (int kt = 0; kt < 8; ++kt) {
    const int k0 = kt * 64;
    __syncthreads();
#pragma unroll
    for (int it = 0; it < 4; ++it) {
      int c = tid + it * 256;
      int row = c >> 3, c8 = c & 7;
      *reinterpret_cast<uint4*>(At + swz(row, c8 * 16)) =
          *reinterpret_cast<const uint4*>(oh + (size_t)(m0 + row) * 512 + k0 + c8 * 8);
      *reinterpret_cast<uint4*>(Bt + swz(row, c8 * 16)) =
          *reinterpret_cast<const uint4*>(woT + (size_t)(n0 + row) * 512 + k0 + c8 * 8);
    }
    __syncthreads();
#pragma unroll
    for (int kk = 0; kk < 2; ++kk) {
      bf16x8 a4[4], b4[4];
      const int kb = (kk * 32 + 8 * g) * 2;
#pragma unroll
      for (int mi = 0; mi < 4; ++mi)
        a4[mi] = *reinterpret_cast<const bf16x8*>(At + swz(wm * 64 + mi * 16 + r, kb));
#pragma unroll
      for (int ni = 0; ni < 4; ++ni)
        b4[ni] = *reinterpret_cast<const bf16x8*>(Bt + swz(wn * 64 + ni * 16 + r, kb));
#pragma unroll
      for (int mi = 0; mi < 4; ++mi)
#pragma unroll
        for (int ni = 0; ni < 4; ++ni)
          acc[mi][ni] = MFMA16(a4[mi], b4[ni], acc[mi][ni]);
    }
  }
#pragma unroll
  for (int mi = 0; mi < 4; ++mi)
#pragma unroll
    for (int ni = 0; ni < 4; ++ni)
#pragma unroll
      for (int i = 0; i < 4; ++i) {
        int m = m0 + wm * 64 + mi * 16 + 4 * g + i;
        int n = n0 + wn * 64 + ni * 16 + r;
        float v = acc[mi][ni][i] + b_out[n];
        __builtin_nontemporal_store(v, out + (size_t)m * 512 + n);
      }
}

extern "C" void kernel_launch(void* const* d_in, const int* in_sizes, int n_in,
                              void* d_out, int out_size, void* d_ws, size_t ws_size,
                              hipStream_t stream) {
  // Bind inputs BY SIZE (all six element counts distinct) — immune to order.
  const float *x = nullptr, *w_qkv = nullptr, *w_out = nullptr,
              *b_out = nullptr, *rpe = nullptr;
  const int* hop = nullptr;
  for (int i = 0; i < n_in; ++i) {
    switch (in_sizes[i]) {
      case 4194304: x     = (const float*)d_in[i]; break;  // (8,1024,512)
      case 786432:  w_qkv = (const float*)d_in[i]; break;  // (512,1536)
      case 262144:  w_out = (const float*)d_in[i]; break;  // (512,512)
      case 512:     b_out = (const float*)d_in[i]; break;  // (512,)
      case 72:      rpe   = (const float*)d_in[i]; break;  // (8,9)
      case 1048576: hop   = (const int*)d_in[i];   break;  // (1024,1024) int32
    }
  }

  float* out  = (float*)d_out;                 // f32 outputs
  float* attn = out + (size_t)4194304;         // attn section (8,8,1024,1024)

  char* ws = (char*)d_ws;
  unsigned short* q_    = (unsigned short*)(ws);                   // 8 MB
  unsigned short* k_    = (unsigned short*)(ws + (size_t) 8388608);// 8 MB
  unsigned short* valT  = (unsigned short*)(ws + (size_t)16777216);// 8 MB
  unsigned short* oh    = (unsigned short*)(ws + (size_t)25165824);// 8 MB
  unsigned short* wqT   = (unsigned short*)(ws + (size_t)33554432);// 1.5 MB
  unsigned short* woT   = (unsigned short*)(ws + (size_t)35127296);// 0.5 MB
  unsigned short* biasT = (unsigned short*)(ws + (size_t)35651584);// 16 MB
  unsigned short* xb    = (unsigned short*)(ws + (size_t)52428800);// 8 MB
  // total ~60 MB of d_ws

  // merged prep grid: 786432 wqT + 262144 woT + 1048576 xb-quads + 1048576 bias
  k_prep<<<dim3(12288), dim3(256), 0, stream>>>(w_qkv, w_out, x, hop, rpe,
                                                wqT, woT, xb, biasT);
  k_qkv<<<dim3(64, 12), dim3(256), 0, stream>>>(xb, wqT, q_, k_, valT);
  k_attn<<<dim3(4096), dim3(256), 0, stream>>>(q_, k_, valT, biasT, attn, oh);
  k_out<<<dim3(64, 4), dim3(256), 0, stream>>>(oh, woT, b_out, out);
}

// Round 18
// 194.027 us; speedup vs baseline: 1.0706x; 1.0706x over previous
//
#include <hip/hip_runtime.h>

typedef __attribute__((ext_vector_type(8))) short bf16x8;
typedef __attribute__((ext_vector_type(4))) float f32x4;

#define MFMA16(A,B,C) __builtin_amdgcn_mfma_f32_16x16x32_bf16(A,B,C,0,0,0)

__device__ __forceinline__ unsigned short f2bf(float f){
  unsigned int u = __float_as_uint(f);
  u += 0x7FFFu + ((u >> 16) & 1u);        // round-to-nearest-even
  return (unsigned short)(u >> 16);
}
__device__ __forceinline__ float bf2f(unsigned short s){
  return __uint_as_float(((unsigned int)s) << 16);
}
// byte offset into a [rows][64] bf16 LDS tile (128B rows), XOR-swizzled (G4)
__device__ __forceinline__ int swz(int row, int kbyte){
  return (row * 128 + kbyte) ^ ((row & 7) << 4);
}

// -- prep (merged, tiled-transpose): blocks 0-255 transpose wqT/woT via LDS
//    (64x64 f32 tile, [64][65] padding); 256-1279 xb convert; 1280+ bias.
__global__ __launch_bounds__(256) void k_prep(
    const float* __restrict__ w_qkv, const float* __restrict__ w_out,
    const float* __restrict__ x,
    const int* __restrict__ hop, const float* __restrict__ rpe_bias,
    unsigned short* __restrict__ wqT, unsigned short* __restrict__ woT,
    unsigned short* __restrict__ xb, unsigned short* __restrict__ biasT)
{
  __shared__ float tile[64][65];
  __shared__ float rl[72];
  const int bid = blockIdx.x, tid = threadIdx.x;
  if (bid < 256) {
    // tiled transpose: coalesced reads along n, coalesced writes along kq
    const float* src; unsigned short* dst; int srcld, kq0, n0;
    if (bid < 192) {                       // wqT: 24 n-tiles x 8 kq-tiles
      int tn = bid >> 3, tk = bid & 7;
      src = w_qkv; dst = wqT; srcld = 1536; kq0 = tk * 64; n0 = tn * 64;
    } else {                               // woT: 8 x 8 tiles
      int j = bid - 192; int tn = j >> 3, tk = j & 7;
      src = w_out; dst = woT; srcld = 512; kq0 = tk * 64; n0 = tn * 64;
    }
    const int c = tid & 63, r4 = tid >> 6;
#pragma unroll
    for (int i = 0; i < 16; ++i) {
      int rr = r4 * 16 + i;
      tile[rr][c] = src[(size_t)(kq0 + rr) * srcld + n0 + c];
    }
    __syncthreads();
#pragma unroll
    for (int i = 0; i < 16; ++i) {
      int rr = r4 * 16 + i;                // output row = n index
      dst[(size_t)(n0 + rr) * 512 + kq0 + c] = f2bf(tile[c][rr]);
    }
  } else if (bid < 1280) {                 // xb: 1024 blocks x 1024 quads
    int base = (bid - 256) * 1024 + tid;
#pragma unroll
    for (int i = 0; i < 4; ++i) {
      int j = base + i * 256;
      float4 xv = *reinterpret_cast<const float4*>(x + (size_t)j * 4);
      ushort4 o;
      o.x = f2bf(xv.x); o.y = f2bf(xv.y); o.z = f2bf(xv.z); o.w = f2bf(xv.w);
      *reinterpret_cast<ushort4*>(xb + (size_t)j * 4) = o;
    }
  } else {                                 // bias: 4096 blocks, coalesced
    if (tid < 72) rl[tid] = rpe_bias[tid];
    __syncthreads();
    int j = (bid - 1280) * 256 + tid;
    int hv = hop[j];
#pragma unroll
    for (int h = 0; h < 8; ++h)
      biasT[((size_t)h << 20) + j] = f2bf(rl[h * 9 + hv]);
  }
}

// ---------------- QKV GEMM: qkv = xb @ w_qkv (MFMA, bf16 in / f32 acc) -----
__global__ __launch_bounds__(256) void k_qkv(
    const unsigned short* __restrict__ xb, const unsigned short* __restrict__ wqT,
    unsigned short* __restrict__ q, unsigned short* __restrict__ k_,
    unsigned short* __restrict__ valT)
{
  __shared__ char lds[32768];
  char* At = lds; char* Bt = lds + 16384;
  const int tid = threadIdx.x;
  const int wid = tid >> 6, lane = tid & 63, g = lane >> 4, r = lane & 15;
  const int wm = wid >> 1, wn = wid & 1;
  const int m0 = blockIdx.x * 128, n0 = blockIdx.y * 128;

  f32x4 acc[4][4];
#pragma unroll
  for (int a = 0; a < 4; ++a)
#pragma unroll
    for (int b = 0; b < 4; ++b) acc[a][b] = (f32x4){0.f, 0.f, 0.f, 0.f};

  for (int kt = 0; kt < 8; ++kt) {
    const int k0 = kt * 64;
    __syncthreads();
#pragma unroll
    for (int it = 0; it < 4; ++it) {
      int c = tid + it * 256;            // 128 rows x 8 chunks(16B)
      int row = c >> 3, c8 = c & 7;
      *reinterpret_cast<uint4*>(At + swz(row, c8 * 16)) =
          *reinterpret_cast<const uint4*>(xb + (size_t)(m0 + row) * 512 + k0 + c8 * 8);
      *reinterpret_cast<uint4*>(Bt + swz(row, c8 * 16)) =
          *reinterpret_cast<const uint4*>(wqT + (size_t)(n0 + row) * 512 + k0 + c8 * 8);
    }
    __syncthreads();
#pragma unroll
    for (int kk = 0; kk < 2; ++kk) {
      bf16x8 af[4], bf[4];
      const int kb = (kk * 32 + 8 * g) * 2;
#pragma unroll
      for (int mi = 0; mi < 4; ++mi)
        af[mi] = *reinterpret_cast<const bf16x8*>(At + swz(wm * 64 + mi * 16 + r, kb));
#pragma unroll
      for (int ni = 0; ni < 4; ++ni)
        bf[ni] = *reinterpret_cast<const bf16x8*>(Bt + swz(wn * 64 + ni * 16 + r, kb));
#pragma unroll
      for (int mi = 0; mi < 4; ++mi)
#pragma unroll
        for (int ni = 0; ni < 4; ++ni)
          acc[mi][ni] = MFMA16(af[mi], bf[ni], acc[mi][ni]);
    }
  }
  const int s = n0 >> 9;  // 0=q 1=k 2=val
#pragma unroll
  for (int mi = 0; mi < 4; ++mi)
#pragma unroll
    for (int ni = 0; ni < 4; ++ni)
#pragma unroll
      for (int i = 0; i < 4; ++i) {
        int m = m0 + wm * 64 + mi * 16 + 4 * g + i;   // D row = 4g+i (m89)
        int n = n0 + wn * 64 + ni * 16 + r;           // D col = lane&15
        int b = m >> 10, v = m & 1023;
        int cc = n & 511, h = cc >> 6, d = cc & 63;
        int bh = b * 8 + h;
        unsigned short bfv = f2bf(acc[mi][ni][i]);
        if (s == 2)      valT[((size_t)bh * 64 + d) * 1024 + v] = bfv;
        else if (s == 0) q [((size_t)bh * 1024 + v) * 64 + d] = bfv;
        else             k_[((size_t)bh * 1024 + v) * 64 + d] = bfv;
      }
}

// ---------------- attention (r14 best config): regs-scores + shfl softmax --
// One block = (b,h, 16 q-rows). Wave w owns score cols [256w, 256w+256).
// Work order (h, vt, b) with b INNERMOST; XCD j owns head h=j.
#define PSTR 1032
__global__ __launch_bounds__(256, 4) void k_attn(
    const unsigned short* __restrict__ q, const unsigned short* __restrict__ k_,
    const unsigned short* __restrict__ valT,
    const unsigned short* __restrict__ biasT,
    float* __restrict__ attn, unsigned short* __restrict__ oh)
{
  __shared__ unsigned short P[16 * PSTR];   // bf16, 33 KB
  __shared__ float red[2][4][16];
  const int tid = threadIdx.x;
  const int wid = tid >> 6, lane = tid & 63, g = lane >> 4, r = lane & 15;
  // bijective XCD swizzle (4096 % 8 == 0): XCD j gets work ids [512j, 512j+512)
  const int blk = ((blockIdx.x & 7) << 9) | (blockIdx.x >> 3);
  const int h  = blk >> 9;                  // outermost: one head per XCD
  const int vt = (blk >> 3) & 63;
  const int b  = blk & 7;                   // innermost: bias-tile sharers adjacent
  const int bh = b * 8 + h;
  const int v0 = vt * 16;

  // stage bias tile [16 rows][1024 w] bf16 into P (uint4 = 8 elems, coalesced)
  const unsigned short* bb = biasT + ((size_t)h << 20) + (size_t)v0 * 1024;
#pragma unroll
  for (int it = 0; it < 8; ++it) {
    int e = tid + it * 256;                  // 0..2047: row=e>>7, chunk=e&127
    int row = e >> 7, c8 = e & 127;
    *reinterpret_cast<uint4*>(&P[row * PSTR + c8 * 8]) =
        *reinterpret_cast<const uint4*>(bb + (size_t)row * 1024 + c8 * 8);
  }

  // Q fragments in registers (A-operand: row=r, k-slice 8g)
  const unsigned short* qp = q + ((size_t)bh * 1024 + v0) * 64;
  bf16x8 qf[2];
#pragma unroll
  for (int kk = 0; kk < 2; ++kk)
    qf[kk] = *reinterpret_cast<const bf16x8*>(qp + r * 64 + kk * 32 + 8 * g);
  __syncthreads();

  // QK: scores in registers; bias from LDS
  const unsigned short* kb = k_ + (size_t)bh * 65536;
  f32x4 s[16];
#pragma unroll
  for (int ct = 0; ct < 16; ++ct) {
    const int wcol = wid * 256 + ct * 16 + r;
    f32x4 acc = (f32x4){0.f, 0.f, 0.f, 0.f};
#pragma unroll
    for (int kk = 0; kk < 2; ++kk) {
      bf16x8 kf = *reinterpret_cast<const bf16x8*>(kb + (size_t)wcol * 64 + kk * 32 + 8 * g);
      acc = MFMA16(qf[kk], kf, acc);
    }
#pragma unroll
    for (int i = 0; i < 4; ++i)
      s[ct][i] = (acc[i] + bf2f(P[(4 * g + i) * PSTR + wcol])) * 0.125f;
  }

  // per-row max: local over ct, then shfl over the 16-lane r-group
  float mx[4] = {-1e30f, -1e30f, -1e30f, -1e30f};
#pragma unroll
  for (int ct = 0; ct < 16; ++ct)
#pragma unroll
    for (int i = 0; i < 4; ++i) mx[i] = fmaxf(mx[i], s[ct][i]);
#pragma unroll
  for (int o = 1; o <= 8; o <<= 1)
#pragma unroll
    for (int i = 0; i < 4; ++i) mx[i] = fmaxf(mx[i], __shfl_xor(mx[i], o, 64));
  if (r == 0)
#pragma unroll
    for (int i = 0; i < 4; ++i) red[0][wid][4 * g + i] = mx[i];
  __syncthreads();
#pragma unroll
  for (int i = 0; i < 4; ++i) {
    float M = red[0][0][4 * g + i];
#pragma unroll
    for (int w = 1; w < 4; ++w) M = fmaxf(M, red[0][w][4 * g + i]);
    mx[i] = M;
  }

  // exp + per-row sum
  float sm[4] = {0.f, 0.f, 0.f, 0.f};
#pragma unroll
  for (int ct = 0; ct < 16; ++ct)
#pragma unroll
    for (int i = 0; i < 4; ++i) {
      float e = __expf(s[ct][i] - mx[i]);
      s[ct][i] = e;
      sm[i] += e;
    }
#pragma unroll
  for (int o = 1; o <= 8; o <<= 1)
#pragma unroll
    for (int i = 0; i < 4; ++i) sm[i] += __shfl_xor(sm[i], o, 64);
  if (r == 0)
#pragma unroll
    for (int i = 0; i < 4; ++i) red[1][wid][4 * g + i] = sm[i];
  __syncthreads();                 // all QK bias reads done before P overwrite
  float inv[4];
#pragma unroll
  for (int i = 0; i < 4; ++i) {
    float T = red[1][0][4 * g + i] + red[1][1][4 * g + i] +
              red[1][2][4 * g + i] + red[1][3][4 * g + i];
    inv[i] = 1.0f / T;
  }

  // normalize into bf16 P only (no scattered global writes)
#pragma unroll
  for (int ct = 0; ct < 16; ++ct) {
    const int col = wid * 256 + ct * 16 + r;
#pragma unroll
    for (int i = 0; i < 4; ++i)
      P[(4 * g + i) * PSTR + col] = f2bf(s[ct][i] * inv[i]);
  }
  __syncthreads();

  // coalesced attn write from P: lane -> f32x4 (16B) nontemporal, 1KB/wave.
  float* ab = attn + ((size_t)bh * 1024 + v0) * 1024;
#pragma unroll
  for (int it = 0; it < 16; ++it) {
    int e = tid + it * 256;                 // 0..4095: row=e>>8, quad=e&255
    int row = e >> 8, q4 = e & 255;
    uint2 pv = *reinterpret_cast<const uint2*>(&P[row * PSTR + q4 * 4]);
    f32x4 o;
    o[0] = bf2f((unsigned short)(pv.x      ));
    o[1] = bf2f((unsigned short)(pv.x >> 16));
    o[2] = bf2f((unsigned short)(pv.y      ));
    o[3] = bf2f((unsigned short)(pv.y >> 16));
    __builtin_nontemporal_store(o, reinterpret_cast<f32x4*>(ab + (size_t)row * 1024 + q4 * 4));
  }

  // PV: out(16x64) = P(16x1024) @ val(1024x64); wave owns 16 out cols.
  const unsigned short* vT = valT + ((size_t)bh * 64 + wid * 16) * 1024;
  f32x4 a0 = (f32x4){0.f,0.f,0.f,0.f}, a1 = a0;
  for (int kc = 0; kc < 32; kc += 2) {
    const int base = r * PSTR, vbase = kc * 32 + 8 * g;
    bf16x8 p0 = *reinterpret_cast<const bf16x8*>(&P[base + vbase]);
    bf16x8 p1 = *reinterpret_cast<const bf16x8*>(&P[base + vbase + 32]);
    bf16x8 v0_ = *reinterpret_cast<const bf16x8*>(vT + (size_t)r * 1024 + vbase);
    bf16x8 v1_ = *reinterpret_cast<const bf16x8*>(vT + (size_t)r * 1024 + vbase + 32);
    a0 = MFMA16(p0, v0_, a0);
    a1 = MFMA16(p1, v1_, a1);
  }
  f32x4 acc = a0 + a1;
#pragma unroll
  for (int i = 0; i < 4; ++i) {
    size_t oi = ((size_t)(b * 1024 + v0 + 4 * g + i)) * 512 + h * 64 + wid * 16 + r;
    oh[oi] = f2bf(acc[i]);
  }
}

// ---------------- output GEMM: out = oh @ w_out + b_out (f32 out) ----------
__global__ __launch_bounds__(256) void k_out(
    const unsigned short* __restrict__ oh, const unsigned short* __restrict__ woT,
    const float* __restrict__ b_out, float* __restrict__ out)
{
  __shared__ char lds[32768];
  char* At = lds; char* Bt = lds + 16384;
  const int tid = threadIdx.x;
  const int wid = tid >> 6, lane = tid & 63, g = lane >> 4, r = lane & 15;
  const int wm = wid >> 1, wn = wid & 1;
  const int m0 = blockIdx.x * 128, n0 = blockIdx.y * 128;

  f32x4 acc[4][4];
#pragma unroll
  for (int a = 0; a < 4; ++a)
#pragma unroll
    for (int b = 0; b < 4; ++b) acc[a][b] = (f32x4){0.f, 0.f, 0.f, 0.f};

  for (int kt = 0; kt < 8; ++kt) {
    const int k0 = kt * 64;
    __syncthreads();
#pragma unroll
    for (int it = 0; it < 4; ++it) {
      int c = tid + it * 256;
      int row = c >> 3, c8 = c & 7;
      *reinterpret_cast<uint4*>(At + swz(row, c8 * 16)) =
          *reinterpret_cast<const uint4*>(oh + (size_t)(m0 + row) * 512 + k0 + c8 * 8);
      *reinterpret_cast<uint4*>(Bt + swz(row, c8 * 16)) =
          *reinterpret_cast<const uint4*>(woT + (size_t)(n0 + row) * 512 + k0 + c8 * 8);
    }
    __syncthreads();
#pragma unroll
    for (int kk = 0; kk < 2; ++kk) {
      bf16x8 a4[4], b4[4];
      const int kb = (kk * 32 + 8 * g) * 2;
#pragma unroll
      for (int mi = 0; mi < 4; ++mi)
        a4[mi] = *reinterpret_cast<const bf16x8*>(At + swz(wm * 64 + mi * 16 + r, kb));
#pragma unroll
      for (int ni = 0; ni < 4; ++ni)
        b4[ni] = *reinterpret_cast<const bf16x8*>(Bt + swz(wn * 64 + ni * 16 + r, kb));
#pragma unroll
      for (int mi = 0; mi < 4; ++mi)
#pragma unroll
        for (int ni = 0; ni < 4; ++ni)
          acc[mi][ni] = MFMA16(a4[mi], b4[ni], acc[mi][ni]);
    }
  }
#pragma unroll
  for (int mi = 0; mi < 4; ++mi)
#pragma unroll
    for (int ni = 0; ni < 4; ++ni)
#pragma unroll
      for (int i = 0; i < 4; ++i) {
        int m = m0 + wm * 64 + mi * 16 + 4 * g + i;
        int n = n0 + wn * 64 + ni * 16 + r;
        float v = acc[mi][ni][i] + b_out[n];
        __builtin_nontemporal_store(v, out + (size_t)m * 512 + n);
      }
}

extern "C" void kernel_launch(void* const* d_in, const int* in_sizes, int n_in,
                              void* d_out, int out_size, void* d_ws, size_t ws_size,
                              hipStream_t stream) {
  // Bind inputs BY SIZE (all six element counts distinct) — immune to order.
  const float *x = nullptr, *w_qkv = nullptr, *w_out = nullptr,
              *b_out = nullptr, *rpe = nullptr;
  const int* hop = nullptr;
  for (int i = 0; i < n_in; ++i) {
    switch (in_sizes[i]) {
      case 4194304: x     = (const float*)d_in[i]; break;  // (8,1024,512)
      case 786432:  w_qkv = (const float*)d_in[i]; break;  // (512,1536)
      case 262144:  w_out = (const float*)d_in[i]; break;  // (512,512)
      case 512:     b_out = (const float*)d_in[i]; break;  // (512,)
      case 72:      rpe   = (const float*)d_in[i]; break;  // (8,9)
      case 1048576: hop   = (const int*)d_in[i];   break;  // (1024,1024) int32
    }
  }

  float* out  = (float*)d_out;                 // f32 outputs
  float* attn = out + (size_t)4194304;         // attn section (8,8,1024,1024)

  char* ws = (char*)d_ws;
  unsigned short* q_    = (unsigned short*)(ws);                   // 8 MB
  unsigned short* k_    = (unsigned short*)(ws + (size_t) 8388608);// 8 MB
  unsigned short* valT  = (unsigned short*)(ws + (size_t)16777216);// 8 MB
  unsigned short* oh    = (unsigned short*)(ws + (size_t)25165824);// 8 MB
  unsigned short* wqT   = (unsigned short*)(ws + (size_t)33554432);// 1.5 MB
  unsigned short* woT   = (unsigned short*)(ws + (size_t)35127296);// 0.5 MB
  unsigned short* biasT = (unsigned short*)(ws + (size_t)35651584);// 16 MB
  unsigned short* xb    = (unsigned short*)(ws + (size_t)52428800);// 8 MB
  // total ~60 MB of d_ws

  // prep grid: 256 transpose tiles + 1024 xb blocks + 4096 bias blocks
  k_prep<<<dim3(5376), dim3(256), 0, stream>>>(w_qkv, w_out, x, hop, rpe,
                                               wqT, woT, xb, biasT);
  k_qkv<<<dim3(64, 12), dim3(256), 0, stream>>>(xb, wqT, q_, k_, valT);
  k_attn<<<dim3(4096), dim3(256), 0, stream>>>(q_, k_, valT, biasT, attn, oh);
  k_out<<<dim3(64, 4), dim3(256), 0, stream>>>(oh, woT, b_out, out);
}

// Round 19
// 193.908 us; speedup vs baseline: 1.0713x; 1.0006x over previous
//
#include <hip/hip_runtime.h>

typedef __attribute__((ext_vector_type(8))) short bf16x8;
typedef __attribute__((ext_vector_type(4))) float f32x4;

#define MFMA16(A,B,C) __builtin_amdgcn_mfma_f32_16x16x32_bf16(A,B,C,0,0,0)

typedef const __attribute__((address_space(1))) void gas_t;
typedef __attribute__((address_space(3))) void las_t;
#define GLOAD16(g, l) __builtin_amdgcn_global_load_lds((gas_t*)(g), (las_t*)(l), 16, 0, 0)

__device__ __forceinline__ unsigned short f2bf(float f){
  unsigned int u = __float_as_uint(f);
  u += 0x7FFFu + ((u >> 16) & 1u);        // round-to-nearest-even
  return (unsigned short)(u >> 16);
}
__device__ __forceinline__ float bf2f(unsigned short s){
  return __uint_as_float(((unsigned int)s) << 16);
}
// byte offset into a [rows][64] bf16 LDS tile (128B rows), XOR-swizzled (G4)
__device__ __forceinline__ int swz(int row, int kbyte){
  return (row * 128 + kbyte) ^ ((row & 7) << 4);
}

// -- prep (merged, tiled-transpose): blocks 0-255 transpose wqT/woT via LDS
//    (64x64 f32 tile, [64][65] padding); 256-1279 xb convert; 1280+ bias.
__global__ __launch_bounds__(256) void k_prep(
    const float* __restrict__ w_qkv, const float* __restrict__ w_out,
    const float* __restrict__ x,
    const int* __restrict__ hop, const float* __restrict__ rpe_bias,
    unsigned short* __restrict__ wqT, unsigned short* __restrict__ woT,
    unsigned short* __restrict__ xb, unsigned short* __restrict__ biasT)
{
  __shared__ float tile[64][65];
  __shared__ float rl[72];
  const int bid = blockIdx.x, tid = threadIdx.x;
  if (bid < 256) {
    // tiled transpose: coalesced reads along n, coalesced writes along kq
    const float* src; unsigned short* dst; int srcld, kq0, n0;
    if (bid < 192) {                       // wqT: 24 n-tiles x 8 kq-tiles
      int tn = bid >> 3, tk = bid & 7;
      src = w_qkv; dst = wqT; srcld = 1536; kq0 = tk * 64; n0 = tn * 64;
    } else {                               // woT: 8 x 8 tiles
      int j = bid - 192; int tn = j >> 3, tk = j & 7;
      src = w_out; dst = woT; srcld = 512; kq0 = tk * 64; n0 = tn * 64;
    }
    const int c = tid & 63, r4 = tid >> 6;
#pragma unroll
    for (int i = 0; i < 16; ++i) {
      int rr = r4 * 16 + i;
      tile[rr][c] = src[(size_t)(kq0 + rr) * srcld + n0 + c];
    }
    __syncthreads();
#pragma unroll
    for (int i = 0; i < 16; ++i) {
      int rr = r4 * 16 + i;                // output row = n index
      dst[(size_t)(n0 + rr) * 512 + kq0 + c] = f2bf(tile[c][rr]);
    }
  } else if (bid < 1280) {                 // xb: 1024 blocks x 1024 quads
    int base = (bid - 256) * 1024 + tid;
#pragma unroll
    for (int i = 0; i < 4; ++i) {
      int j = base + i * 256;
      float4 xv = *reinterpret_cast<const float4*>(x + (size_t)j * 4);
      ushort4 o;
      o.x = f2bf(xv.x); o.y = f2bf(xv.y); o.z = f2bf(xv.z); o.w = f2bf(xv.w);
      *reinterpret_cast<ushort4*>(xb + (size_t)j * 4) = o;
    }
  } else {                                 // bias: 4096 blocks, coalesced
    if (tid < 72) rl[tid] = rpe_bias[tid];
    __syncthreads();
    int j = (bid - 1280) * 256 + tid;
    int hv = hop[j];
#pragma unroll
    for (int h = 0; h < 8; ++h)
      biasT[((size_t)h << 20) + j] = f2bf(rl[h * 9 + hv]);
  }
}

// ------- QKV GEMM: qkv = xb @ w_qkv, async global_load_lds staging ---------
// LDS dest linear (HW requirement); global SOURCE pre-swizzled with the same
// XOR involution that swz() applies on the read side (m173 both-sides rule):
// lane l writes lds row with row&7 == l>>3, so src col = ((l&7)^(l>>3))*8.
__global__ __launch_bounds__(256) void k_qkv(
    const unsigned short* __restrict__ xb, const unsigned short* __restrict__ wqT,
    unsigned short* __restrict__ q, unsigned short* __restrict__ k_,
    unsigned short* __restrict__ valT)
{
  __shared__ char lds[32768];
  char* At = lds; char* Bt = lds + 16384;
  const int tid = threadIdx.x;
  const int wid = tid >> 6, lane = tid & 63, g = lane >> 4, r = lane & 15;
  const int wm = wid >> 1, wn = wid & 1;
  const int m0 = blockIdx.x * 128, n0 = blockIdx.y * 128;
  const int l8 = lane >> 3;
  const int colel = ((lane & 7) ^ l8) * 8;   // pre-swizzled source column (elems)

  f32x4 acc[4][4];
#pragma unroll
  for (int a = 0; a < 4; ++a)
#pragma unroll
    for (int b = 0; b < 4; ++b) acc[a][b] = (f32x4){0.f, 0.f, 0.f, 0.f};

  for (int kt = 0; kt < 8; ++kt) {
    const int k0 = kt * 64;
    __syncthreads();
#pragma unroll
    for (int i = 0; i < 4; ++i) {
      int row = wid * 32 + i * 8 + l8;
      GLOAD16(xb  + (size_t)(m0 + row) * 512 + k0 + colel, At + wid * 4096 + i * 1024);
      GLOAD16(wqT + (size_t)(n0 + row) * 512 + k0 + colel, Bt + wid * 4096 + i * 1024);
    }
    __syncthreads();
#pragma unroll
    for (int kk = 0; kk < 2; ++kk) {
      bf16x8 af[4], bf[4];
      const int kb = (kk * 32 + 8 * g) * 2;
#pragma unroll
      for (int mi = 0; mi < 4; ++mi)
        af[mi] = *reinterpret_cast<const bf16x8*>(At + swz(wm * 64 + mi * 16 + r, kb));
#pragma unroll
      for (int ni = 0; ni < 4; ++ni)
        bf[ni] = *reinterpret_cast<const bf16x8*>(Bt + swz(wn * 64 + ni * 16 + r, kb));
#pragma unroll
      for (int mi = 0; mi < 4; ++mi)
#pragma unroll
        for (int ni = 0; ni < 4; ++ni)
          acc[mi][ni] = MFMA16(af[mi], bf[ni], acc[mi][ni]);
    }
  }
  const int s = n0 >> 9;  // 0=q 1=k 2=val
#pragma unroll
  for (int mi = 0; mi < 4; ++mi)
#pragma unroll
    for (int ni = 0; ni < 4; ++ni)
#pragma unroll
      for (int i = 0; i < 4; ++i) {
        int m = m0 + wm * 64 + mi * 16 + 4 * g + i;   // D row = 4g+i (m89)
        int n = n0 + wn * 64 + ni * 16 + r;           // D col = lane&15
        int b = m >> 10, v = m & 1023;
        int cc = n & 511, h = cc >> 6, d = cc & 63;
        int bh = b * 8 + h;
        unsigned short bfv = f2bf(acc[mi][ni][i]);
        if (s == 2)      valT[((size_t)bh * 64 + d) * 1024 + v] = bfv;
        else if (s == 0) q [((size_t)bh * 1024 + v) * 64 + d] = bfv;
        else             k_[((size_t)bh * 1024 + v) * 64 + d] = bfv;
      }
}

// ---------------- attention (r14/r18 best config, unchanged) ---------------
#define PSTR 1032
__global__ __launch_bounds__(256, 4) void k_attn(
    const unsigned short* __restrict__ q, const unsigned short* __restrict__ k_,
    const unsigned short* __restrict__ valT,
    const unsigned short* __restrict__ biasT,
    float* __restrict__ attn, unsigned short* __restrict__ oh)
{
  __shared__ unsigned short P[16 * PSTR];   // bf16, 33 KB
  __shared__ float red[2][4][16];
  const int tid = threadIdx.x;
  const int wid = tid >> 6, lane = tid & 63, g = lane >> 4, r = lane & 15;
  // bijective XCD swizzle (4096 % 8 == 0): XCD j gets work ids [512j, 512j+512)
  const int blk = ((blockIdx.x & 7) << 9) | (blockIdx.x >> 3);
  const int h  = blk >> 9;                  // outermost: one head per XCD
  const int vt = (blk >> 3) & 63;
  const int b  = blk & 7;                   // innermost: bias-tile sharers adjacent
  const int bh = b * 8 + h;
  const int v0 = vt * 16;

  // stage bias tile [16 rows][1024 w] bf16 into P (uint4 = 8 elems, coalesced)
  const unsigned short* bb = biasT + ((size_t)h << 20) + (size_t)v0 * 1024;
#pragma unroll
  for (int it = 0; it < 8; ++it) {
    int e = tid + it * 256;                  // 0..2047: row=e>>7, chunk=e&127
    int row = e >> 7, c8 = e & 127;
    *reinterpret_cast<uint4*>(&P[row * PSTR + c8 * 8]) =
        *reinterpret_cast<const uint4*>(bb + (size_t)row * 1024 + c8 * 8);
  }

  // Q fragments in registers (A-operand: row=r, k-slice 8g)
  const unsigned short* qp = q + ((size_t)bh * 1024 + v0) * 64;
  bf16x8 qf[2];
#pragma unroll
  for (int kk = 0; kk < 2; ++kk)
    qf[kk] = *reinterpret_cast<const bf16x8*>(qp + r * 64 + kk * 32 + 8 * g);
  __syncthreads();

  // QK: scores in registers; bias from LDS
  const unsigned short* kb = k_ + (size_t)bh * 65536;
  f32x4 s[16];
#pragma unroll
  for (int ct = 0; ct < 16; ++ct) {
    const int wcol = wid * 256 + ct * 16 + r;
    f32x4 acc = (f32x4){0.f, 0.f, 0.f, 0.f};
#pragma unroll
    for (int kk = 0; kk < 2; ++kk) {
      bf16x8 kf = *reinterpret_cast<const bf16x8*>(kb + (size_t)wcol * 64 + kk * 32 + 8 * g);
      acc = MFMA16(qf[kk], kf, acc);
    }
#pragma unroll
    for (int i = 0; i < 4; ++i)
      s[ct][i] = (acc[i] + bf2f(P[(4 * g + i) * PSTR + wcol])) * 0.125f;
  }

  // per-row max: local over ct, then shfl over the 16-lane r-group
  float mx[4] = {-1e30f, -1e30f, -1e30f, -1e30f};
#pragma unroll
  for (int ct = 0; ct < 16; ++ct)
#pragma unroll
    for (int i = 0; i < 4; ++i) mx[i] = fmaxf(mx[i], s[ct][i]);
#pragma unroll
  for (int o = 1; o <= 8; o <<= 1)
#pragma unroll
    for (int i = 0; i < 4; ++i) mx[i] = fmaxf(mx[i], __shfl_xor(mx[i], o, 64));
  if (r == 0)
#pragma unroll
    for (int i = 0; i < 4; ++i) red[0][wid][4 * g + i] = mx[i];
  __syncthreads();
#pragma unroll
  for (int i = 0; i < 4; ++i) {
    float M = red[0][0][4 * g + i];
#pragma unroll
    for (int w = 1; w < 4; ++w) M = fmaxf(M, red[0][w][4 * g + i]);
    mx[i] = M;
  }

  // exp + per-row sum
  float sm[4] = {0.f, 0.f, 0.f, 0.f};
#pragma unroll
  for (int ct = 0; ct < 16; ++ct)
#pragma unroll
    for (int i = 0; i < 4; ++i) {
      float e = __expf(s[ct][i] - mx[i]);
      s[ct][i] = e;
      sm[i] += e;
    }
#pragma unroll
  for (int o = 1; o <= 8; o <<= 1)
#pragma unroll
    for (int i = 0; i < 4; ++i) sm[i] += __shfl_xor(sm[i], o, 64);
  if (r == 0)
#pragma unroll
    for (int i = 0; i < 4; ++i) red[1][wid][4 * g + i] = sm[i];
  __syncthreads();                 // all QK bias reads done before P overwrite
  float inv[4];
#pragma unroll
  for (int i = 0; i < 4; ++i) {
    float T = red[1][0][4 * g + i] + red[1][1][4 * g + i] +
              red[1][2][4 * g + i] + red[1][3][4 * g + i];
    inv[i] = 1.0f / T;
  }

  // normalize into bf16 P only (no scattered global writes)
#pragma unroll
  for (int ct = 0; ct < 16; ++ct) {
    const int col = wid * 256 + ct * 16 + r;
#pragma unroll
    for (int i = 0; i < 4; ++i)
      P[(4 * g + i) * PSTR + col] = f2bf(s[ct][i] * inv[i]);
  }
  __syncthreads();

  // coalesced attn write from P: lane -> f32x4 (16B) nontemporal, 1KB/wave.
  float* ab = attn + ((size_t)bh * 1024 + v0) * 1024;
#pragma unroll
  for (int it = 0; it < 16; ++it) {
    int e = tid + it * 256;                 // 0..4095: row=e>>8, quad=e&255
    int row = e >> 8, q4 = e & 255;
    uint2 pv = *reinterpret_cast<const uint2*>(&P[row * PSTR + q4 * 4]);
    f32x4 o;
    o[0] = bf2f((unsigned short)(pv.x      ));
    o[1] = bf2f((unsigned short)(pv.x >> 16));
    o[2] = bf2f((unsigned short)(pv.y      ));
    o[3] = bf2f((unsigned short)(pv.y >> 16));
    __builtin_nontemporal_store(o, reinterpret_cast<f32x4*>(ab + (size_t)row * 1024 + q4 * 4));
  }

  // PV: out(16x64) = P(16x1024) @ val(1024x64); wave owns 16 out cols.
  const unsigned short* vT = valT + ((size_t)bh * 64 + wid * 16) * 1024;
  f32x4 a0 = (f32x4){0.f,0.f,0.f,0.f}, a1 = a0;
  for (int kc = 0; kc < 32; kc += 2) {
    const int base = r * PSTR, vbase = kc * 32 + 8 * g;
    bf16x8 p0 = *reinterpret_cast<const bf16x8*>(&P[base + vbase]);
    bf16x8 p1 = *reinterpret_cast<const bf16x8*>(&P[base + vbase + 32]);
    bf16x8 v0_ = *reinterpret_cast<const bf16x8*>(vT + (size_t)r * 1024 + vbase);
    bf16x8 v1_ = *reinterpret_cast<const bf16x8*>(vT + (size_t)r * 1024 + vbase + 32);
    a0 = MFMA16(p0, v0_, a0);
    a1 = MFMA16(p1, v1_, a1);
  }
  f32x4 acc = a0 + a1;
#pragma unroll
  for (int i = 0; i < 4; ++i) {
    size_t oi = ((size_t)(b * 1024 + v0 + 4 * g + i)) * 512 + h * 64 + wid * 16 + r;
    oh[oi] = f2bf(acc[i]);
  }
}

// ------- output GEMM: out = oh @ w_out + b_out, async staging --------------
__global__ __launch_bounds__(256) void k_out(
    const unsigned short* __restrict__ oh, const unsigned short* __restrict__ woT,
    const float* __restrict__ b_out, float* __restrict__ out)
{
  __shared__ char lds[32768];
  char* At = lds; char* Bt = lds + 16384;
  const int tid = threadIdx.x;
  const int wid = tid >> 6, lane = tid & 63, g = lane >> 4, r = lane & 15;
  const int wm = wid >> 1, wn = wid & 1;
  const int m0 = blockIdx.x * 128, n0 = blockIdx.y * 128;
  const int l8 = lane >> 3;
  const int colel = ((lane & 7) ^ l8) * 8;   // pre-swizzled source column (elems)

  f32x4 acc[4][4];
#pragma unroll
  for (int a = 0; a < 4; ++a)
#pragma unroll
    for (int b = 0; b < 4; ++b) acc[a][b] = (f32x4){0.f, 0.f, 0.f, 0.f};

  for (int kt = 0; kt < 8; ++kt) {
    const int k0 = kt * 64;
    __syncthreads();
#pragma unroll
    for (int i = 0; i < 4; ++i) {
      int row = wid * 32 + i * 8 + l8;
      GLOAD16(oh  + (size_t)(m0 + row) * 512 + k0 + colel, At + wid * 4096 + i * 1024);
      GLOAD16(woT + (size_t)(n0 + row) * 512 + k0 + colel, Bt + wid * 4096 + i * 1024);
    }
    __syncthreads();
#pragma unroll
    for (int kk = 0; kk < 2; ++kk) {
      bf16x8 a4[4], b4[4];
      const int kb = (kk * 32 + 8 * g) * 2;
#pragma unroll
      for (int mi = 0; mi < 4; ++mi)
        a4[mi] = *reinterpret_cast<const bf16x8*>(At + swz(wm * 64 + mi * 16 + r, kb));
#pragma unroll
      for (int ni = 0; ni < 4; ++ni)
        b4[ni] = *reinterpret_cast<const bf16x8*>(Bt + swz(wn * 64 + ni * 16 + r, kb));
#pragma unroll
      for (int mi = 0; mi < 4; ++mi)
#pragma unroll
        for (int ni = 0; ni < 4; ++ni)
          acc[mi][ni] = MFMA16(a4[mi], b4[ni], acc[mi][ni]);
    }
  }
#pragma unroll
  for (int mi = 0; mi < 4; ++mi)
#pragma unroll
    for (int ni = 0; ni < 4; ++ni)
#pragma unroll
      for (int i = 0; i < 4; ++i) {
        int m = m0 + wm * 64 + mi * 16 + 4 * g + i;
        int n = n0 + wn * 64 + ni * 16 + r;
        float v = acc[mi][ni][i] + b_out[n];
        __builtin_nontemporal_store(v, out + (size_t)m * 512 + n);
      }
}

extern "C" void kernel_launch(void* const* d_in, const int* in_sizes, int n_in,
                              void* d_out, int out_size, void* d_ws, size_t ws_size,
                              hipStream_t stream) {
  // Bind inputs BY SIZE (all six element counts distinct) — immune to order.
  const float *x = nullptr, *w_qkv = nullptr, *w_out = nullptr,
              *b_out = nullptr, *rpe = nullptr;
  const int* hop = nullptr;
  for (int i = 0; i < n_in; ++i) {
    switch (in_sizes[i]) {
      case 4194304: x     = (const float*)d_in[i]; break;  // (8,1024,512)
      case 786432:  w_qkv = (const float*)d_in[i]; break;  // (512,1536)
      case 262144:  w_out = (const float*)d_in[i]; break;  // (512,512)
      case 512:     b_out = (const float*)d_in[i]; break;  // (512,)
      case 72:      rpe   = (const float*)d_in[i]; break;  // (8,9)
      case 1048576: hop   = (const int*)d_in[i];   break;  // (1024,1024) int32
    }
  }

  float* out  = (float*)d_out;                 // f32 outputs
  float* attn = out + (size_t)4194304;         // attn section (8,8,1024,1024)

  char* ws = (char*)d_ws;
  unsigned short* q_    = (unsigned short*)(ws);                   // 8 MB
  unsigned short* k_    = (unsigned short*)(ws + (size_t) 8388608);// 8 MB
  unsigned short* valT  = (unsigned short*)(ws + (size_t)16777216);// 8 MB
  unsigned short* oh    = (unsigned short*)(ws + (size_t)25165824);// 8 MB
  unsigned short* wqT   = (unsigned short*)(ws + (size_t)33554432);// 1.5 MB
  unsigned short* woT   = (unsigned short*)(ws + (size_t)35127296);// 0.5 MB
  unsigned short* biasT = (unsigned short*)(ws + (size_t)35651584);// 16 MB
  unsigned short* xb    = (unsigned short*)(ws + (size_t)52428800);// 8 MB
  // total ~60 MB of d_ws

  // prep grid: 256 transpose tiles + 1024 xb blocks + 4096 bias blocks
  k_prep<<<dim3(5376), dim3(256), 0, stream>>>(w_qkv, w_out, x, hop, rpe,
                                               wqT, woT, xb, biasT);
  k_qkv<<<dim3(64, 12), dim3(256), 0, stream>>>(xb, wqT, q_, k_, valT);
  k_attn<<<dim3(4096), dim3(256), 0, stream>>>(q_, k_, valT, biasT, attn, oh);
  k_out<<<dim3(64, 4), dim3(256), 0, stream>>>(oh, woT, b_out, out);
}